// Round 11
// baseline (395.554 us; speedup 1.0000x reference)
//
#include <hip/hip_runtime.h>
#include <stdint.h>

#define NVN 50000
#define NUN 50000
#define NB 49          // buckets of 1024 nodes per side
#define CH 4096        // edges per bucket_scatter block
#define HCH 8192       // edges per histogram block (in prep)
#define BCAP 24576     // LDS staging capacity (edges) in bucket_build

typedef __attribute__((ext_vector_type(8))) short short8v;
typedef __attribute__((ext_vector_type(8))) unsigned short ushort8v;
typedef __attribute__((ext_vector_type(4))) float float4v;
typedef __attribute__((ext_vector_type(4))) unsigned uint4v;

__device__ __forceinline__ unsigned short f2bf(float f) {
  union { float f; unsigned u; } x; x.f = f;
  unsigned r = x.u + 0x7FFFu + ((x.u >> 16) & 1u);
  return (unsigned short)(r >> 16);
}
__device__ __forceinline__ float bf2f(unsigned short h) {
  union { unsigned u; float f; } x; x.u = ((unsigned)h) << 16;
  return x.f;
}

// ---- prep: weight convert+transpose, feature f32->bf16, bucket histogram
struct WConvEnt { const float* src; unsigned short* dst; int K; int N; };
struct PrepArgs {
  WConvEnt w[6];
  const float* fv; const float* fu;
  unsigned short* fbv; unsigned short* fbu;
  const int* ev; const int* eu;
  int* bcnt;      // [2*NB]
  int ne;
};
__global__ __launch_bounds__(256) void prep_kernel(PrepArgs a) {
  __shared__ int h[2 * NB];
  int b = blockIdx.x;
  if (b < 768) {  // 6 weights x 128 blocks
    WConvEnt c = a.w[b >> 7];
    int i = (b & 127) * 256 + threadIdx.x;
    int k = i / c.N, n = i - k * c.N;
    c.dst[(size_t)n * c.K + k] = f2bf(c.src[i]);  // Wt[N][K]
    return;
  }
  b -= 768;
  if (b < 6250) {  // features: 3125 blocks per side, 8 elems/thread
    const float* src = (b < 3125) ? a.fv : a.fu;
    unsigned short* dst = (b < 3125) ? a.fbv : a.fbu;
    int bb = (b < 3125) ? b : b - 3125;
    size_t base = ((size_t)bb * 256 + threadIdx.x) * 8;
    float4 x = *(const float4*)(src + base);
    float4 y = *(const float4*)(src + base + 4);
    ushort8v r;
    r[0] = f2bf(x.x); r[1] = f2bf(x.y); r[2] = f2bf(x.z); r[3] = f2bf(x.w);
    r[4] = f2bf(y.x); r[5] = f2bf(y.y); r[6] = f2bf(y.z); r[7] = f2bf(y.w);
    *(ushort8v*)(dst + base) = r;
    return;
  }
  b -= 6250;  // bucket histogram over an HCH-edge chunk
  const int tid = threadIdx.x;
  for (int j = tid; j < 2 * NB; j += 256) h[j] = 0;
  __syncthreads();
  const int e0 = b * HCH;
  const int e1 = min(e0 + HCH, a.ne);
  for (int i = e0 + tid; i < e1; i += 256) {
    atomicAdd(&h[a.ev[i] >> 10], 1);
    atomicAdd(&h[NB + (a.eu[i] >> 10)], 1);
  }
  __syncthreads();
  for (int j = tid; j < 2 * NB; j += 256)
    if (h[j]) atomicAdd(&a.bcnt[j], h[j]);
}

// ---- phase A: pack edges into bucket-major staged records.
__global__ __launch_bounds__(256) void bucket_scatter(
    const int* __restrict__ ev, const int* __restrict__ eu,
    const int* __restrict__ bcnt, int* __restrict__ bcur,
    unsigned* __restrict__ stg_v, unsigned* __restrict__ stg_u, int ne) {
  __shared__ int cnt[NB];
  __shared__ int pos[NB];
  __shared__ int gbase[NB];
  __shared__ int bb_s[NB];
  __shared__ unsigned rec[CH];
  const int side = blockIdx.y;
  const int* key = side ? eu : ev;
  const int* pay = side ? ev : eu;
  unsigned* stg = side ? stg_u : stg_v;
  const int tid = threadIdx.x;
  const int e0 = blockIdx.x * CH;
  const int e1 = min(e0 + CH, ne);
  if (tid < NB) cnt[tid] = 0;
  __syncthreads();
  if (tid >= 64 && tid < 128) {  // wave 1: scan bucket counts -> bases
    int t = tid - 64;
    int c = (t < NB) ? bcnt[side * NB + t] : 0;
    int x = c;
#pragma unroll
    for (int s = 1; s < 64; s <<= 1) {
      int tt = __shfl_up(x, (unsigned)s, 64);
      if (t >= s) x += tt;
    }
    if (t < NB) bb_s[t] = x - c;
  }
  for (int i = e0 + tid; i < e1; i += 256) atomicAdd(&cnt[key[i] >> 10], 1);
  __syncthreads();
  if (tid < 64) {
    int c = (tid < NB) ? cnt[tid] : 0;
    int x = c;
#pragma unroll
    for (int s = 1; s < 64; s <<= 1) {
      int t = __shfl_up(x, (unsigned)s, 64);
      if (tid >= s) x += t;
    }
    if (tid < NB) pos[tid] = x - c;  // exclusive prefix
  }
  __syncthreads();
  for (int i = e0 + tid; i < e1; i += 256) {
    int k = key[i];
    int b = k >> 10;
    int p = atomicAdd(&pos[b], 1);
    rec[p] = ((unsigned)(k & 1023) << 16) | (unsigned)pay[i];
  }
  __syncthreads();
  if (tid < NB)
    gbase[tid] = bb_s[tid] + atomicAdd(&bcur[side * NB + tid], cnt[tid]);
  __syncthreads();
  for (int b = 0; b < NB; ++b) {
    int c = cnt[b];
    int lbase = pos[b] - c;
    int gb = gbase[b];
    for (int i = tid; i < c; i += 256) stg[gb + i] = rec[lbase + i];
  }
}

// ---- phase B: per-bucket CSR finalize; also writes per-node off[]
__global__ __launch_bounds__(256) void bucket_build(
    int* __restrict__ off_v, int* __restrict__ off_u,
    const int* __restrict__ bcnt,
    const unsigned* __restrict__ stg_v, const unsigned* __restrict__ stg_u,
    unsigned short* __restrict__ csr_v, unsigned short* __restrict__ csr_u,
    int nv, int nu) {
  __shared__ int cur[1024];
  __shared__ int wred[4];
  __shared__ int wbase[4];
  __shared__ int bb_s[NB + 1];
  __shared__ unsigned short st[BCAP];
  const int side = blockIdx.y;
  int* off = side ? off_u : off_v;
  const unsigned* stg = side ? stg_u : stg_v;
  unsigned short* csr = side ? csr_u : csr_v;
  const int n = side ? nu : nv;
  const int tid = threadIdx.x;
  const int lane = tid & 63;
  const int w = tid >> 6;
  if (tid < 64) {  // scan bucket counts -> bases
    int c = (tid < NB) ? bcnt[side * NB + tid] : 0;
    int x = c;
#pragma unroll
    for (int s = 1; s < 64; s <<= 1) {
      int t = __shfl_up(x, (unsigned)s, 64);
      if (tid >= s) x += t;
    }
    if (tid <= NB) bb_s[tid] = x - c;  // bb_s[NB] = total
  }
  for (int j = tid; j < 1024; j += 256) cur[j] = 0;
  __syncthreads();
  const int nbase = blockIdx.x << 10;
  const int nb = min(1024, n - nbase);
  const int ebase = bb_s[blockIdx.x];
  const int cnt = bb_s[blockIdx.x + 1] - ebase;
  for (int i = tid; i < cnt; i += 256) atomicAdd(&cur[stg[ebase + i] >> 16], 1);
  __syncthreads();
  // exclusive scan of 1024 counts: thread owns 4 consecutive
  const int j0 = tid * 4;
  int c0 = cur[j0], c1 = cur[j0 + 1], c2 = cur[j0 + 2], c3 = cur[j0 + 3];
  int tsum = c0 + c1 + c2 + c3;
  int x = tsum;
#pragma unroll
  for (int s = 1; s < 64; s <<= 1) {
    int t = __shfl_up(x, (unsigned)s, 64);
    if (lane >= s) x += t;
  }
  if (lane == 63) wred[w] = x;
  __syncthreads();
  if (tid == 0) {
    int a = 0;
    for (int k = 0; k < 4; ++k) { wbase[k] = a; a += wred[k]; }
  }
  __syncthreads();
  const int ex = wbase[w] + (x - tsum);
  cur[j0] = ex;
  cur[j0 + 1] = ex + c0;
  cur[j0 + 2] = ex + c0 + c1;
  cur[j0 + 3] = ex + c0 + c1 + c2;
  __syncthreads();
  for (int j = tid; j < nb; j += 256) off[nbase + j] = ebase + cur[j];
  if (nbase + nb == n && tid == 0) off[n] = ebase + cnt;
  __syncthreads();
  if (cnt <= BCAP) {
    for (int i = tid; i < cnt; i += 256) {
      unsigned r = stg[ebase + i];
      int p = atomicAdd(&cur[r >> 16], 1);
      st[p] = (unsigned short)(r & 0xFFFFu);
    }
    __syncthreads();
    for (int i = tid; i < cnt; i += 256) csr[ebase + i] = st[i];
  } else {  // safety fallback
    for (int i = tid; i < cnt; i += 256) {
      unsigned r = stg[ebase + i];
      int p = atomicAdd(&cur[r >> 16], 1);
      csr[ebase + p] = (unsigned short)(r & 0xFFFFu);
    }
  }
}

// --------------------------------------------------- gather-aggregate d=128
// One wave per destination row. 4 row-groups x 16 lanes; each group loads a
// DIFFERENT neighbor row via dwordx4. 16-deep unroll => 16 rows (4 loads/lane)
// in flight. Non-temporal output stores keep the source table L2-resident.
struct GSide {
  const unsigned* src;             // bf16x2 rows, 64 uints/row
  const unsigned short* csr; const int* off;
  const float* bias; const float* slope;
  const unsigned* own;             // bf16x2 rows (mode 2)
  void* dst; int ldo;              // ldo in dst elements
};

__device__ __forceinline__ void acc8(float* acc, uint4v p) {
  acc[0] += bf2f((unsigned short)p.x);
  acc[1] += bf2f((unsigned short)(p.x >> 16));
  acc[2] += bf2f((unsigned short)p.y);
  acc[3] += bf2f((unsigned short)(p.y >> 16));
  acc[4] += bf2f((unsigned short)p.z);
  acc[5] += bf2f((unsigned short)(p.z >> 16));
  acc[6] += bf2f((unsigned short)p.w);
  acc[7] += bf2f((unsigned short)(p.w >> 16));
}

template <int MODE>
__global__ __launch_bounds__(256) void gatherk(GSide g0, GSide g1, int n) {
  GSide g = blockIdx.y ? g1 : g0;
  int wid = (int)(((size_t)blockIdx.x * 256 + threadIdx.x) >> 6);
  if (wid >= n) return;
  const int lane = threadIdx.x & 63;
  const int grp = lane >> 4;    // row group 0..3
  const int lc = lane & 15;     // 8-col slot
  const int s = g.off[wid], e = g.off[wid + 1];
  const int cnt = e - s;
  float acc[8] = {0.f, 0.f, 0.f, 0.f, 0.f, 0.f, 0.f, 0.f};
  int idx = 0;
  if (lane < cnt) idx = (int)g.csr[s + lane];
  const int m = cnt < 64 ? cnt : 64;
  int j = 0;
  for (; j + 15 < m; j += 16) {
    int r0 = __shfl(idx, j + grp, 64);
    int r1 = __shfl(idx, j + 4 + grp, 64);
    int r2 = __shfl(idx, j + 8 + grp, 64);
    int r3 = __shfl(idx, j + 12 + grp, 64);
    uint4v p0 = *((const uint4v*)(g.src + (size_t)r0 * 64) + lc);
    uint4v p1 = *((const uint4v*)(g.src + (size_t)r1 * 64) + lc);
    uint4v p2 = *((const uint4v*)(g.src + (size_t)r2 * 64) + lc);
    uint4v p3 = *((const uint4v*)(g.src + (size_t)r3 * 64) + lc);
    acc8(acc, p0);
    acc8(acc, p1);
    acc8(acc, p2);
    acc8(acc, p3);
  }
  for (; j + 3 < m; j += 4) {
    int r0 = __shfl(idx, j + grp, 64);
    uint4v p0 = *((const uint4v*)(g.src + (size_t)r0 * 64) + lc);
    acc8(acc, p0);
  }
  if (j < m) {
    int jj = j + grp;
    int r0 = __shfl(idx, jj < m ? jj : 0, 64);
    if (jj < m) {
      uint4v p0 = *((const uint4v*)(g.src + (size_t)r0 * 64) + lc);
      acc8(acc, p0);
    }
  }
  for (int i = s + 64 + grp; i < e; i += 4) {  // rare (deg > 64)
    int r0 = (int)g.csr[i];
    uint4v p0 = *((const uint4v*)(g.src + (size_t)r0 * 64) + lc);
    acc8(acc, p0);
  }
  // fold the 4 row-groups
#pragma unroll
  for (int k = 0; k < 8; ++k) {
    acc[k] += __shfl_xor(acc[k], 16, 64);
    acc[k] += __shfl_xor(acc[k], 32, 64);
  }
  if (grp != 0) return;
  const float deg = (float)cnt;
  if (MODE == 0) {
    float inv = 1.f / fmaxf(deg, 1.f);
    uint4v o;
    o.x = ((unsigned)f2bf(acc[1] * inv) << 16) | (unsigned)f2bf(acc[0] * inv);
    o.y = ((unsigned)f2bf(acc[3] * inv) << 16) | (unsigned)f2bf(acc[2] * inv);
    o.z = ((unsigned)f2bf(acc[5] * inv) << 16) | (unsigned)f2bf(acc[4] * inv);
    o.w = ((unsigned)f2bf(acc[7] * inv) << 16) | (unsigned)f2bf(acc[6] * inv);
    __builtin_nontemporal_store(o, (uint4v*)((unsigned*)g.dst + (size_t)wid * g.ldo) + lc);
  } else if (MODE == 1) {
    float inv = 1.f / fmaxf(deg, 1.f);
    float sl = g.slope[0];
    float4 b0 = *(const float4*)(g.bias + lc * 8);
    float4 b1 = *(const float4*)(g.bias + lc * 8 + 4);
    float o[8];
    o[0] = acc[0] * inv + b0.x; o[1] = acc[1] * inv + b0.y;
    o[2] = acc[2] * inv + b0.z; o[3] = acc[3] * inv + b0.w;
    o[4] = acc[4] * inv + b1.x; o[5] = acc[5] * inv + b1.y;
    o[6] = acc[6] * inv + b1.z; o[7] = acc[7] * inv + b1.w;
#pragma unroll
    for (int k = 0; k < 8; ++k) o[k] = o[k] >= 0.f ? o[k] : o[k] * sl;
    float* dp = (float*)g.dst + (size_t)wid * g.ldo + lc * 8;
    float4v o0 = {o[0], o[1], o[2], o[3]};
    float4v o1 = {o[4], o[5], o[6], o[7]};
    __builtin_nontemporal_store(o0, (float4v*)dp);
    __builtin_nontemporal_store(o1, (float4v*)(dp + 4));
  } else {
    float inv = 1.f / (deg + 1.f);
    uint4v ow = *((const uint4v*)(g.own + (size_t)wid * 64) + lc);
    float o[8];
    o[0] = (acc[0] + bf2f((unsigned short)ow.x)) * inv;
    o[1] = (acc[1] + bf2f((unsigned short)(ow.x >> 16))) * inv;
    o[2] = (acc[2] + bf2f((unsigned short)ow.y)) * inv;
    o[3] = (acc[3] + bf2f((unsigned short)(ow.y >> 16))) * inv;
    o[4] = (acc[4] + bf2f((unsigned short)ow.z)) * inv;
    o[5] = (acc[5] + bf2f((unsigned short)(ow.z >> 16))) * inv;
    o[6] = (acc[6] + bf2f((unsigned short)ow.w)) * inv;
    o[7] = (acc[7] + bf2f((unsigned short)(ow.w >> 16))) * inv;
    float* dp = (float*)g.dst + (size_t)wid * g.ldo + lc * 8;
    float4v o0 = {o[0], o[1], o[2], o[3]};
    float4v o1 = {o[4], o[5], o[6], o[7]};
    __builtin_nontemporal_store(o0, (float4v*)dp);
    __builtin_nontemporal_store(o1, (float4v*)(dp + 4));
  }
}

// -------------------- fused GEMM1+GEMM2: T = prelu(A@W1+b1) @ W2
struct Gm12Side {
  const unsigned short* A;
  const unsigned short* Wt1;
  const float* bias1; const float* slope1;
  const unsigned short* Wt2;
  unsigned short* T;
};

__global__ __launch_bounds__(256) void gemm12(Gm12Side s0, Gm12Side s1, int M) {
  __shared__ unsigned short e1[64][264];  // pad 8
  const Gm12Side s = blockIdx.z ? s1 : s0;
  const int tid = threadIdx.x;
  const int wv = tid >> 6;
  const int lane = tid & 63;
  const int lc = lane & 15;
  const int khi = lane >> 4;
  const int bm = blockIdx.x * 64;

  // phase 1
  short8v b1[4][4];
#pragma unroll
  for (int kb = 0; kb < 4; ++kb)
#pragma unroll
    for (int f = 0; f < 4; ++f)
      b1[kb][f] = *(const short8v*)(s.Wt1 + (size_t)(wv * 64 + f * 16 + lc) * 128 +
                                    kb * 32 + khi * 8);
  short8v a[4][4];
#pragma unroll
  for (int rt = 0; rt < 4; ++rt) {
    const int row = bm + rt * 16 + lc;
#pragma unroll
    for (int kb = 0; kb < 4; ++kb) {
      if (row < M)
        a[rt][kb] = *(const short8v*)(s.A + (size_t)row * 128 + kb * 32 + khi * 8);
      else
        a[rt][kb] = (short8v){0, 0, 0, 0, 0, 0, 0, 0};
    }
  }
  float4v acc[4][4];
#pragma unroll
  for (int rt = 0; rt < 4; ++rt)
#pragma unroll
    for (int f = 0; f < 4; ++f) acc[rt][f] = (float4v){0.f, 0.f, 0.f, 0.f};
#pragma unroll
  for (int kb = 0; kb < 4; ++kb)
#pragma unroll
    for (int rt = 0; rt < 4; ++rt)
#pragma unroll
      for (int f = 0; f < 4; ++f)
        acc[rt][f] = __builtin_amdgcn_mfma_f32_16x16x32_bf16(a[rt][kb], b1[kb][f],
                                                             acc[rt][f], 0, 0, 0);
  const float sl = s.slope1[0];
#pragma unroll
  for (int f = 0; f < 4; ++f) {
    const int col = wv * 64 + f * 16 + lc;
    const float bv = s.bias1[col];
#pragma unroll
    for (int rt = 0; rt < 4; ++rt)
#pragma unroll
      for (int i = 0; i < 4; ++i) {
        float v = acc[rt][f][i] + bv;
        if (v < 0.f) v *= sl;
        e1[rt * 16 + khi * 4 + i][col] = f2bf(v);
      }
  }
  __syncthreads();

  // phase 2
  short8v b2[8][2];
#pragma unroll
  for (int kb = 0; kb < 8; ++kb)
#pragma unroll
    for (int f = 0; f < 2; ++f)
      b2[kb][f] = *(const short8v*)(s.Wt2 + (size_t)(wv * 32 + f * 16 + lc) * 256 +
                                    kb * 32 + khi * 8);
  float4v acc2[4][2];
#pragma unroll
  for (int rt = 0; rt < 4; ++rt)
#pragma unroll
    for (int f = 0; f < 2; ++f) acc2[rt][f] = (float4v){0.f, 0.f, 0.f, 0.f};
#pragma unroll
  for (int kb = 0; kb < 8; ++kb) {
    short8v a2[4];
#pragma unroll
    for (int rt = 0; rt < 4; ++rt)
      a2[rt] = *(const short8v*)(&e1[rt * 16 + lc][kb * 32 + khi * 8]);
#pragma unroll
    for (int rt = 0; rt < 4; ++rt)
#pragma unroll
      for (int f = 0; f < 2; ++f)
        acc2[rt][f] = __builtin_amdgcn_mfma_f32_16x16x32_bf16(a2[rt], b2[kb][f],
                                                              acc2[rt][f], 0, 0, 0);
  }
#pragma unroll
  for (int f = 0; f < 2; ++f) {
    const int col = wv * 32 + f * 16 + lc;
#pragma unroll
    for (int rt = 0; rt < 4; ++rt)
#pragma unroll
      for (int i = 0; i < 4; ++i) {
        const int row = bm + rt * 16 + khi * 4 + i;
        if (row < M) s.T[(size_t)row * 128 + col] = f2bf(acc2[rt][f][i]);
      }
  }
}

// ------------------------------------------- MFMA GEMM, register-resident B
struct GmSide {
  const void* A1; const void* A2;
  const unsigned short* Wt;
  const float* bias; const float* slope;
  void* C;
};

template <int BF>
__device__ __forceinline__ short8v load_a8(const void* A, size_t off) {
  if (BF) {
    return *(const short8v*)((const unsigned short*)A + off);
  } else {
    const float* p = (const float*)A + off;
    float4 x = *(const float4*)p;
    float4 y = *(const float4*)(p + 4);
    short8v r;
    r[0] = (short)f2bf(x.x); r[1] = (short)f2bf(x.y);
    r[2] = (short)f2bf(x.z); r[3] = (short)f2bf(x.w);
    r[4] = (short)f2bf(y.x); r[5] = (short)f2bf(y.y);
    r[6] = (short)f2bf(y.z); r[7] = (short)f2bf(y.w);
    return r;
  }
}

#define TILES 5  // 16-row tiles per block; 50000 = 625*5*16 exactly

template <int KB1, int KB2, int NF, int A1BF, int A2BF, int CBF, int ACT>
__global__ __launch_bounds__(256) void gemm_reg(GmSide s0, GmSide s1,
                                                int lda1, int lda2,
                                                int ldc, int M) {
  constexpr int KB = KB1 + KB2;
  GmSide s = blockIdx.z ? s1 : s0;
  const int K = KB * 32;
  const int tid = threadIdx.x;
  const int wv = tid >> 6;
  const int lane = tid & 63;
  const int lc = lane & 15;
  const int khi = lane >> 4;
  const int bm = blockIdx.x * (16 * TILES);
  const int colbase = wv * (NF * 16);

  short8v b[KB][NF];
#pragma unroll
  for (int kb = 0; kb < KB; ++kb)
#pragma unroll
    for (int f = 0; f < NF; ++f)
      b[kb][f] = *(const short8v*)(s.Wt + (size_t)(colbase + f * 16 + lc) * K +
                                   kb * 32 + khi * 8);

  const float sl = ACT ? s.slope[0] : 0.f;
  float bias_f[NF];
#pragma unroll
  for (int f = 0; f < NF; ++f)
    bias_f[f] = s.bias ? s.bias[colbase + f * 16 + lc] : 0.f;

  short8v a_cur[KB], a_nxt[KB];
  {
    const int rowa = bm + lc;
#pragma unroll
    for (int kb = 0; kb < KB; ++kb) {
      if (kb < KB1)
        a_cur[kb] = load_a8<A1BF>(s.A1, (size_t)rowa * lda1 + kb * 32 + khi * 8);
      else
        a_cur[kb] = load_a8<A2BF>(s.A2, (size_t)rowa * lda2 + (kb - KB1) * 32 + khi * 8);
    }
  }

  for (int t = 0; t < TILES; ++t) {
    if (t + 1 < TILES) {
      const int rowa = bm + (t + 1) * 16 + lc;
#pragma unroll
      for (int kb = 0; kb < KB; ++kb) {
        if (kb < KB1)
          a_nxt[kb] = load_a8<A1BF>(s.A1, (size_t)rowa * lda1 + kb * 32 + khi * 8);
        else
          a_nxt[kb] = load_a8<A2BF>(s.A2, (size_t)rowa * lda2 + (kb - KB1) * 32 + khi * 8);
      }
    }
    float4v acc[NF];
#pragma unroll
    for (int f = 0; f < NF; ++f) acc[f] = (float4v){0.f, 0.f, 0.f, 0.f};
#pragma unroll
    for (int kb = 0; kb < KB; ++kb)
#pragma unroll
      for (int f = 0; f < NF; ++f)
        acc[f] = __builtin_amdgcn_mfma_f32_16x16x32_bf16(a_cur[kb], b[kb][f],
                                                         acc[f], 0, 0, 0);
#pragma unroll
    for (int f = 0; f < NF; ++f) {
      const int col = colbase + f * 16 + lc;
#pragma unroll
      for (int i = 0; i < 4; ++i) {
        const int row = bm + t * 16 + khi * 4 + i;
        float v = acc[f][i] + bias_f[f];
        if (ACT && v < 0.f) v *= sl;
        if (CBF) ((unsigned short*)s.C)[(size_t)row * ldc + col] = f2bf(v);
        else     ((float*)s.C)[(size_t)row * ldc + col] = v;
      }
    }
#pragma unroll
    for (int kb = 0; kb < KB; ++kb) a_cur[kb] = a_nxt[kb];
  }
}

extern "C" void kernel_launch(void* const* d_in, const int* in_sizes, int n_in,
                              void* d_out, int out_size, void* d_ws, size_t ws_size,
                              hipStream_t stream) {
  const float* features_v = (const float*)d_in[0];
  const float* features_u = (const float*)d_in[1];
  const int* edge_v = (const int*)d_in[2];
  const int* edge_u = (const int*)d_in[3];
  const float* Wv1 = (const float*)d_in[4];
  const float* bv1 = (const float*)d_in[5];
  const float* av1 = (const float*)d_in[6];
  const float* Wu1 = (const float*)d_in[7];
  const float* bu1 = (const float*)d_in[8];
  const float* au1 = (const float*)d_in[9];
  const float* Wv2 = (const float*)d_in[10];
  const float* bv2 = (const float*)d_in[11];
  const float* av2 = (const float*)d_in[12];
  const float* Wu2 = (const float*)d_in[13];
  const float* bu2 = (const float*)d_in[14];
  const float* au2 = (const float*)d_in[15];
  const float* Wv3 = (const float*)d_in[16];
  const float* bv3 = (const float*)d_in[17];
  const float* Wu3 = (const float*)d_in[18];
  const float* bu3 = (const float*)d_in[19];
  const int ne = in_sizes[2];

  // ---- workspace layout
  int* bcnt = (int*)d_ws;                        // [2*NB]
  int* bcur = bcnt + 2 * NB;                     // [2*NB] relative cursors
  int* off_v = bcur + 2 * NB;                    // [NV+1]
  int* off_u = off_v + NVN + 1;                  // [NU+1]
  unsigned short* csr_v = (unsigned short*)(off_u + NUN + 1);  // [ne]
  unsigned short* csr_u = csr_v + ne;                          // [ne]
  uintptr_t sbase = (((uintptr_t)(csr_u + ne)) + 15) & ~(uintptr_t)15;
  unsigned* stg_v = (unsigned*)sbase;            // [ne]
  unsigned* stg_u = stg_v + ne;                  // [ne]
  unsigned short* P1b = (unsigned short*)(stg_u + ne);  // [NV*128] bf16
  unsigned short* P2b = P1b + (size_t)NVN * 128; // [NU*128] bf16
  unsigned short* Ve3b = P2b + (size_t)NUN * 128;// [NV*128] bf16
  unsigned short* Ue3b = Ve3b + (size_t)NVN * 128;  // [NU*128] bf16
  unsigned short* Wb = Ue3b + (size_t)NUN * 128; // 6*32768 bf16
  unsigned short* Fbv = Wb + 6 * 32768;          // [NV*128] bf16 features_v
  unsigned short* Fbu = Fbv + (size_t)NVN * 128; // [NU*128] bf16 features_u

  float* out_v = (float*)d_out;              // [NV,256]
  float* out_u = out_v + (size_t)NVN * 256;  // [NU,256]

  const int hb = (ne + HCH - 1) / HCH;
  const dim3 gg((NVN * 64) / 256, 2);        // one wave per node, 2 sides
  const dim3 gr(NVN / (16 * TILES), 1, 2);   // 625 blocks, 2 sides
  const dim3 g12((NVN + 63) / 64, 1, 2);     // 782 blocks, 2 sides
  const dim3 gsc((ne + CH - 1) / CH, 2);
  const dim3 gbd(NB, 2);

  // ---- prep: weights -> bf16 Wt[N][K], features -> bf16, bucket histogram
  hipMemsetAsync(bcnt, 0, (size_t)(4 * NB) * 4, stream);
  PrepArgs pa;
  pa.w[0] = {Wv1, Wb + 0 * 32768, 128, 256};
  pa.w[1] = {Wu1, Wb + 1 * 32768, 128, 256};
  pa.w[2] = {Wv2, Wb + 2 * 32768, 256, 128};
  pa.w[3] = {Wu2, Wb + 3 * 32768, 256, 128};
  pa.w[4] = {Wv3, Wb + 4 * 32768, 256, 128};
  pa.w[5] = {Wu3, Wb + 5 * 32768, 256, 128};
  pa.fv = features_v; pa.fu = features_u;
  pa.fbv = Fbv; pa.fbu = Fbu;
  pa.ev = edge_v; pa.eu = edge_u;
  pa.bcnt = bcnt; pa.ne = ne;
  prep_kernel<<<768 + 6250 + hb, 256, 0, stream>>>(pa);
  bucket_scatter<<<gsc, 256, 0, stream>>>(edge_v, edge_u, bcnt, bcur,
                                          stg_v, stg_u, ne);
  bucket_build<<<gbd, 256, 0, stream>>>(off_v, off_u, bcnt, stg_v, stg_u,
                                        csr_v, csr_u, NVN, NUN);

  // ---- stage 1: neighbor means of bf16 features -> bf16
  {
    GSide a{(const unsigned*)Fbu, csr_v, off_v, nullptr, nullptr, nullptr, P1b, 64};
    GSide b{(const unsigned*)Fbv, csr_u, off_u, nullptr, nullptr, nullptr, P2b, 64};
    gatherk<0><<<gg, 256, 0, stream>>>(a, b, NVN);
  }
  // fused: Tv = prelu(P1b@Wv1+bv1)@Wu2 -> P1b ; Tu = prelu(P2b@Wu1+bu1)@Wv2 -> P2b
  {
    Gm12Side a{P1b, Wb + 0 * 32768, bv1, av1, Wb + 3 * 32768, P1b};
    Gm12Side b{P2b, Wb + 1 * 32768, bu1, au1, Wb + 2 * 32768, P2b};
    gemm12<<<g12, 256, 0, stream>>>(a, b, NVN);
  }
  // ---- stage 2: ve2 = prelu(mean_gather(Tu)+bv2) -> out_v[:,0:128]
  {
    GSide a{(const unsigned*)P2b, csr_v, off_v, bv2, av2, nullptr, out_v, 256};
    GSide b{(const unsigned*)P1b, csr_u, off_u, bu2, au2, nullptr, out_u, 256};
    gatherk<1><<<gg, 256, 0, stream>>>(a, b, NVN);
  }
  // ---- stage 3: ve3 = concat(ve2, fv)@Wv3+bv3 -> Ve3b (bf16)
  {
    GmSide a{out_v, Fbv, Wb + 4 * 32768, bv3, nullptr, Ve3b};
    GmSide b{out_u, Fbu, Wb + 5 * 32768, bu3, nullptr, Ue3b};
    gemm_reg<4, 4, 2, 0, 1, 1, 0><<<gr, 256, 0, stream>>>(a, b, 256, 128, 128, NVN);
  }
  // sv = (gather_sum(Ue3b)+Ve3b)/(deg_v+1) -> out_v[:,128:256]
  {
    GSide a{(const unsigned*)Ue3b, csr_v, off_v, nullptr, nullptr,
            (const unsigned*)Ve3b, out_v + 128, 256};
    GSide b{(const unsigned*)Ve3b, csr_u, off_u, nullptr, nullptr,
            (const unsigned*)Ue3b, out_u + 128, 256};
    gatherk<2><<<gg, 256, 0, stream>>>(a, b, NVN);
  }
}